// Round 12
// baseline (882.760 us; speedup 1.0000x reference)
//
#include <hip/hip_runtime.h>
#include <hip/hip_bf16.h>

#define TOKENS 2048
#define HDIM   2560
#define NEXP   16
#define IDIM   1664
#define ISDIM  3328
#define NPAIR  (TOKENS*2)
#define NPERS  768   // persistent blocks (3/CU x 256), 128 threads each

typedef float  f32x4   __attribute__((ext_vector_type(4)));
typedef __bf16 bf16x8  __attribute__((ext_vector_type(8)));
typedef short  short8v __attribute__((ext_vector_type(8)));

#define GLDS16(g, l) __builtin_amdgcn_global_load_lds( \
    (const __attribute__((address_space(1))) unsigned int*)(g), \
    (__attribute__((address_space(3))) unsigned int*)(l), 16, 0, 0)

#define VMCNT(n) asm volatile("s_waitcnt vmcnt(" #n ")" ::: "memory")
#define LGKM_BAR() do { \
    asm volatile("s_waitcnt lgkmcnt(0)" ::: "memory"); \
    __builtin_amdgcn_sched_barrier(0); \
    __builtin_amdgcn_s_barrier(); \
    __builtin_amdgcn_sched_barrier(0); \
  } while (0)
#define PLAIN_BAR() do { \
    __builtin_amdgcn_sched_barrier(0); \
    __builtin_amdgcn_s_barrier(); \
    __builtin_amdgcn_sched_barrier(0); \
  } while (0)

__device__ __forceinline__ short f2bf(float f) {
  unsigned u = __builtin_bit_cast(unsigned, f);
  u += 0x7FFFu + ((u >> 16) & 1u);          // RNE to bf16
  return (short)(u >> 16);
}

// ---------------- router: fp32 logits, softmax-top2-renorm == sigmoid(l0-l1)
__global__ void router_kernel(const float* __restrict__ x, const float* __restrict__ rw,
                              int* __restrict__ counts, int* __restrict__ tidx,
                              float* __restrict__ tw) {
  const int t = blockIdx.x;
  const int lane = threadIdx.x;
  float acc[NEXP];
#pragma unroll
  for (int e = 0; e < NEXP; ++e) acc[e] = 0.f;
  const float* xr = x + (size_t)t * HDIM;
  for (int k = lane; k < HDIM; k += 64) {
    float xv = xr[k];
#pragma unroll
    for (int e = 0; e < NEXP; ++e) acc[e] += xv * rw[e * HDIM + k];
  }
#pragma unroll
  for (int e = 0; e < NEXP; ++e) {
#pragma unroll
    for (int o = 32; o > 0; o >>= 1) acc[e] += __shfl_down(acc[e], o);
  }
  if (lane == 0) {
    int i0 = 0; float v0 = acc[0];
#pragma unroll
    for (int e = 1; e < NEXP; ++e) if (acc[e] > v0) { v0 = acc[e]; i0 = e; }
    int i1 = -1; float v1 = -3.4e38f;
#pragma unroll
    for (int e = 0; e < NEXP; ++e) if (e != i0 && acc[e] > v1) { v1 = acc[e]; i1 = e; }
    float w0 = 1.f / (1.f + expf(v1 - v0));
    tidx[t * 2] = i0; tidx[t * 2 + 1] = i1;
    tw[t * 2] = w0;   tw[t * 2 + 1] = 1.f - w0;
    atomicAdd(&counts[i0], 1);
    atomicAdd(&counts[i1], 1);
  }
}

// scan + tile-queue metadata: meta[0..15]=panel prefix, meta[16]=total panels
__global__ void scan_kernel(const int* __restrict__ counts, int* __restrict__ offsets,
                            int* __restrict__ meta) {
  if (threadIdx.x == 0) {
    int a = 0, p = 0;
    for (int e = 0; e < NEXP; ++e) {
      offsets[e] = a;
      meta[e] = p;
      a += counts[e];
      p += (counts[e] + 127) >> 7;     // ceil(cnt/128) panels
    }
    meta[16] = p;
  }
}

// ---------------- bucket pairs + gather bf16 activations
__global__ void gather_kernel(const float* __restrict__ x, const int* __restrict__ tidx,
                              const float* __restrict__ tw, const int* __restrict__ offsets,
                              int* __restrict__ slotc, int* __restrict__ pairpos,
                              float* __restrict__ wrow, short* __restrict__ xb,
                              short* __restrict__ xg) {
  const int t = blockIdx.x, tid = threadIdx.x;
  __shared__ int grs[2];
  if (tid < 2) {
    int e = tidx[t * 2 + tid];
    int slot = atomicAdd(&slotc[e], 1);
    int g = offsets[e] + slot;
    grs[tid] = g;
    pairpos[t * 2 + tid] = g;
    wrow[g] = tw[t * 2 + tid];
  }
  __syncthreads();
  const int g0 = grs[0], g1 = grs[1];
  const float* xr = x + (size_t)t * HDIM;
#pragma unroll
  for (int i = 0; i < HDIM / 256; ++i) {
    int k = tid + i * 256;
    short v = f2bf(xr[k]);
    xb[(size_t)t * HDIM + k] = v;
    xg[(size_t)g0 * HDIM + k] = v;
    xg[(size_t)g1 * HDIM + k] = v;
  }
}

// ---------------- weight convert: fp32 [K][N] (N-contig) -> bf16 tile-linear,
// pre-swizzled so a linear global_load_lds produces LDS [BN][32] with 16B-unit
// index  n*4 + (koct ^ ((n>>1)&3))  -- matching the GEMM read swizzle exactly.
__global__ void wconv_kernel(const float* __restrict__ src, short* __restrict__ dst,
                             const int K, const int N, const int nT, const int kT,
                             const int BN) {
  const int tid = threadIdx.x;
  int b = blockIdx.x;
  const int kt = b % kT;
  b /= kT;
  const int nt = b % nT;
  const int slab = b / nT;
  const float* s0 = src + (size_t)slab * K * N + (size_t)(kt * 32) * N + nt * BN;
  short8v* d = (short8v*)(dst + ((size_t)((slab * nT + nt) * kT + kt)) * BN * 32);
  const int upt = BN >> 6;                 // units per thread (1 or 2)
  for (int q = 0; q < upt; ++q) {
    const int uidx = tid + q * 256;
    const int n = uidx >> 2;
    const int u = uidx & 3;
    const int koct = u ^ ((n >> 1) & 3);
    const float* s = s0 + (size_t)(koct * 8) * N + n;
    short8v v;
#pragma unroll
    for (int j = 0; j < 8; ++j) v[j] = f2bf(s[(size_t)j * N]);
    d[uidx] = v;
  }
}

// ================= merged UP (persistent, 128 thr = 2 waves):
// H = bf16( silu(A*B1) * (A*B3) ).  Block tile 128m x 64n x {G,U}.
// Wave w: mat (0=G, 1=U), wave tile 128x64 -> 12 ds_read / 32 MFMA per step.
// Depth-3 glds pipeline, 8 glds/thread/step, counted VMCNT(16).
// Conversion tickets (w2, sd fp32 -> swizzled bf16) appended when doconv.
__launch_bounds__(128, 2)
__global__ void moe_up_k(const short* __restrict__ xg, const short* __restrict__ xb,
                         const short* __restrict__ cw1, const short* __restrict__ cw3,
                         const short* __restrict__ csg, const short* __restrict__ csu,
                         short* __restrict__ hbE, short* __restrict__ hbS,
                         const int* __restrict__ counts, const int* __restrict__ offsets,
                         const int* __restrict__ meta,
                         const float* __restrict__ w2f, const float* __restrict__ sdf,
                         short* __restrict__ cw2d, short* __restrict__ csdd,
                         const int doconv) {
  const int tid = threadIdx.x;
  __shared__ int spre[17];
  __shared__ __align__(16) char pool[49152];
  short (*Ab)[128][32] = (short(*)[128][32])pool;             // [3][128][32]  24KB
  short (*Bb)[128][32] = (short(*)[128][32])(pool + 24576);   // [3][G64|U64][32] 24KB
  float* scratch = (float*)pool;                              // 32KB, epilogue only

  if (tid < 17) spre[tid] = meta[tid];
  __syncthreads();
  const int gemmE = spre[16] * 26;
  const int gemmT = gemmE + 832;
  const int total = gemmT + (doconv ? 4680 : 0);

  const int lane = tid & 63;
  const int mat = tid >> 6;         // 0=G, 1=U
  const int lrow = lane & 15;
  const int lkg = lane >> 4;
  const int a_ko = (tid & 3) << 3;

  for (int ticket = blockIdx.x; ticket < total; ticket += NPERS) {
    if (ticket >= gemmT) {
      // ---- conversion ticket: one (col-panel, 4-kt chunk) of w2 or sd
      int ct = ticket - gemmT;
      const float* srcb; short* dstb; int kt0;
      if (ct < 4160) {                       // w2: 320 panels x 13 chunks
        int kc = ct % 13, p = ct / 13;
        int e = p / 20, n = p % 20;
        srcb = w2f + (size_t)e * IDIM * HDIM + n * 128;
        dstb = cw2d + ((size_t)((e * 20 + n) * 52)) * 4096;
        kt0 = kc * 4;
      } else {                               // sd: 20 panels x 26 chunks
        int c2 = ct - 4160;
        int kc = c2 % 26, n = c2 / 26;
        srcb = sdf + n * 128;
        dstb = csdd + ((size_t)(n * 104)) * 4096;
        kt0 = kc * 4;
      }
      for (int kt = kt0; kt < kt0 + 4; ++kt) {
#pragma unroll
        for (int q = 0; q < 4; ++q) {
          int u = tid + (q << 7);
          int nloc = u >> 2;
          int koct = (u & 3) ^ ((nloc >> 1) & 3);
          const float* s = srcb + (size_t)(kt * 32 + koct * 8) * HDIM + nloc;
          short8v v;
#pragma unroll
          for (int j = 0; j < 8; ++j) v[j] = f2bf(s[(size_t)j * HDIM]);
          *reinterpret_cast<short8v*>(dstb + (size_t)kt * 4096 + u * 8) = v;
        }
      }
      continue;
    }

    // ---- GEMM ticket
    const short* A; const short* b1tile; const short* b3tile; short* H;
    int N, mtile, ntile, rowbase = 0, cnt = 0x7fffffff;
    bool expert;
    if (ticket < gemmE) {
      const int p = ticket / 26;
      const int n = ticket % 26;
      int e = 0;
#pragma unroll
      for (int i = 1; i < 16; ++i) if (p >= spre[i]) e = i;
      const int m = p - spre[e];
      cnt = counts[e];
      rowbase = offsets[e];
      mtile = m * 128;
      A = xg;
      b1tile = cw1 + ((size_t)((e * 26 + n) * 80)) * 2048;
      b3tile = cw3 + ((size_t)((e * 26 + n) * 80)) * 2048;
      H = hbE; N = IDIM; ntile = n * 64; expert = true;
    } else {
      const int s = ticket - gemmE;   // 0..831
      const int n = s % 52;
      const int m = s / 52;           // 0..15
      mtile = m * 128;
      A = xb;
      b1tile = csg + ((size_t)(n * 80)) * 2048;
      b3tile = csu + ((size_t)(n * 80)) * 2048;
      H = hbS; N = ISDIM; ntile = n * 64; expert = false;
    }
    const int K = HDIM;
    const int KT = HDIM / 32;         // 80

    f32x4 acc[8][4];
#pragma unroll
    for (int i = 0; i < 8; ++i)
#pragma unroll
      for (int j = 0; j < 4; ++j) { f32x4 z = {0.f,0.f,0.f,0.f}; acc[i][j] = z; }

    // A rows: pass p covers rows (tid>>2) + 32p
    int grp[4];
#pragma unroll
    for (int p = 0; p < 4; ++p) {
      int row = (tid >> 2) + 32 * p;
      int gr = expert ? (rowbase + mtile + row) : (mtile + row);
      if (gr > NPAIR - 1) gr = NPAIR - 1;
      grp[p] = gr;
    }

#define STAGE_U(kt, buf) do { \
    GLDS16(A + (size_t)grp[0] * K + ((kt) << 5) + a_ko, (short*)Ab[buf] + tid * 8); \
    GLDS16(A + (size_t)grp[1] * K + ((kt) << 5) + a_ko, (short*)Ab[buf] + (tid + 128) * 8); \
    GLDS16(A + (size_t)grp[2] * K + ((kt) << 5) + a_ko, (short*)Ab[buf] + (tid + 256) * 8); \
    GLDS16(A + (size_t)grp[3] * K + ((kt) << 5) + a_ko, (short*)Ab[buf] + (tid + 384) * 8); \
    GLDS16(b1tile + (size_t)(kt) * 2048 + tid * 8, (short*)Bb[buf] + tid * 8); \
    GLDS16(b1tile + (size_t)(kt) * 2048 + (tid + 128) * 8, (short*)Bb[buf] + (tid + 128) * 8); \
    GLDS16(b3tile + (size_t)(kt) * 2048 + tid * 8, (short*)Bb[buf] + 2048 + tid * 8); \
    GLDS16(b3tile + (size_t)(kt) * 2048 + (tid + 128) * 8, (short*)Bb[buf] + 2048 + (tid + 128) * 8); \
  } while (0)

    auto compute = [&](int buf) {
      bf16x8 af[8], bfv[4];
#pragma unroll
      for (int mf = 0; mf < 8; ++mf)
        af[mf] = *reinterpret_cast<const bf16x8*>(&Ab[buf][mf * 16 + lrow][lkg << 3]);
#pragma unroll
      for (int nf = 0; nf < 4; ++nf) {
        const int nloc = nf * 16 + lrow;
        const int kg = (lkg ^ ((nloc >> 1) & 3)) << 3;
        bfv[nf] = *reinterpret_cast<const bf16x8*>(&Bb[buf][mat * 64 + nloc][kg]);
      }
#pragma unroll
      for (int mf = 0; mf < 8; ++mf)
#pragma unroll
        for (int nf = 0; nf < 4; ++nf)
          acc[mf][nf] = __builtin_amdgcn_mfma_f32_16x16x32_bf16(af[mf], bfv[nf], acc[mf][nf], 0, 0, 0);
    };

    STAGE_U(0, 0); STAGE_U(1, 1); STAGE_U(2, 2);
    VMCNT(16);
    PLAIN_BAR();

    int cb = 0;
    for (int i = 0; i < KT; ++i) {
      compute(cb);
      LGKM_BAR();
      if (i + 3 < KT)      { STAGE_U(i + 3, cb); VMCNT(16); }
      else if (i + 2 < KT) { VMCNT(8); }
      else if (i + 1 < KT) { VMCNT(0); }
      PLAIN_BAR();
      cb = (cb == 2) ? 0 : cb + 1;
    }

    // epilogue: U-wave exports acc to scratch; G-wave fuses silu(g)*u -> H.
    if (mat) {
#pragma unroll
      for (int mf = 0; mf < 8; ++mf)
#pragma unroll
        for (int r = 0; r < 4; ++r) {
          const int row = mf * 16 + ((lane >> 4) << 2) + r;
#pragma unroll
          for (int nf = 0; nf < 4; ++nf)
            scratch[row * 64 + nf * 16 + lrow] = acc[mf][nf][r];
        }
    }
    LGKM_BAR();
    if (!mat) {
#pragma unroll
      for (int mf = 0; mf < 8; ++mf) {
#pragma unroll
        for (int r = 0; r < 4; ++r) {
          const int row = mf * 16 + ((lane >> 4) << 2) + r;
          if (expert && mtile + row >= cnt) continue;
          const size_t grow = (size_t)((expert ? rowbase : 0) + mtile + row);
          const int colb = ntile + lrow;
#pragma unroll
          for (int nf = 0; nf < 4; ++nf) {
            float g = acc[mf][nf][r];
            float u = scratch[row * 64 + nf * 16 + lrow];
            H[grow * N + colb + nf * 16] = f2bf(g / (1.f + expf(-g)) * u);
          }
        }
      }
    }
    PLAIN_BAR();   // protect scratch/pool from next ticket's staging
#undef STAGE_U
  }
}

// ================= merged DOWN (persistent, 128 thr = 2 waves): Out = A*B.
// Block tile 128m x 128n; wave w = n-half, wave tile 128x64.
// Shared tiles (KT=104) ticketed FIRST so long tiles never start in the tail.
__launch_bounds__(128, 2)
__global__ void moe_dn_k(const short* __restrict__ hbE, const short* __restrict__ hbS,
                         const short* __restrict__ cw2, const short* __restrict__ csd,
                         float* __restrict__ pairs, float* __restrict__ outb,
                         const int* __restrict__ counts, const int* __restrict__ offsets,
                         const float* __restrict__ wrow, const int* __restrict__ meta) {
  const int tid = threadIdx.x;
  __shared__ int spre[17];
  __shared__ short Ab[3][128][32];   // 24 KB, linear
  __shared__ short Bb[3][128][32];   // 24 KB, swizzled [n][k] tile-linear

  if (tid < 17) spre[tid] = meta[tid];
  __syncthreads();
  const int total = spre[16] * 20 + 320;

  const int lane = tid & 63;
  const int wnh = (tid >> 6) * 64;   // n-half
  const int lrow = lane & 15;
  const int lkg = lane >> 4;
  const int a_ko = (tid & 3) << 3;

  for (int ticket = blockIdx.x; ticket < total; ticket += NPERS) {
    const short* A; const short* btile; float* Out;
    int K, KT, mtile, ntile, rowbase = 0, cnt = 0x7fffffff;
    bool expert;
    if (ticket < 320) {               // shared first (long tiles)
      const int n = ticket % 20;
      const int m = ticket / 20;      // 0..15
      mtile = m * 128;
      A = hbS;
      btile = csd + ((size_t)(n * 104)) * 4096;
      Out = outb; K = ISDIM; KT = ISDIM / 32; ntile = n * 128; expert = false; // KT=104
    } else {
      const int te = ticket - 320;
      const int p = te / 20;
      const int n = te % 20;
      int e = 0;
#pragma unroll
      for (int i = 1; i < 16; ++i) if (p >= spre[i]) e = i;
      const int m = p - spre[e];
      cnt = counts[e];
      rowbase = offsets[e];
      mtile = m * 128;
      A = hbE;
      btile = cw2 + ((size_t)((e * 20 + n) * 52)) * 4096;
      Out = pairs; K = IDIM; KT = IDIM / 32; ntile = n * 128; expert = true;   // KT=52
    }

    f32x4 acc[8][4];
#pragma unroll
    for (int i = 0; i < 8; ++i)
#pragma unroll
      for (int j = 0; j < 4; ++j) { f32x4 z = {0.f,0.f,0.f,0.f}; acc[i][j] = z; }

    int grp[4];
#pragma unroll
    for (int p = 0; p < 4; ++p) {
      int row = (tid >> 2) + 32 * p;
      int gr = expert ? (rowbase + mtile + row) : (mtile + row);
      if (gr > NPAIR - 1) gr = NPAIR - 1;
      grp[p] = gr;
    }

#define STAGE_D(kt, buf) do { \
    GLDS16(A + (size_t)grp[0] * K + ((kt) << 5) + a_ko, (short*)Ab[buf] + tid * 8); \
    GLDS16(A + (size_t)grp[1] * K + ((kt) << 5) + a_ko, (short*)Ab[buf] + (tid + 128) * 8); \
    GLDS16(A + (size_t)grp[2] * K + ((kt) << 5) + a_ko, (short*)Ab[buf] + (tid + 256) * 8); \
    GLDS16(A + (size_t)grp[3] * K + ((kt) << 5) + a_ko, (short*)Ab[buf] + (tid + 384) * 8); \
    GLDS16(btile + (size_t)(kt) * 4096 + tid * 8, (short*)Bb[buf] + tid * 8); \
    GLDS16(btile + (size_t)(kt) * 4096 + (tid + 128) * 8, (short*)Bb[buf] + (tid + 128) * 8); \
    GLDS16(btile + (size_t)(kt) * 4096 + (tid + 256) * 8, (short*)Bb[buf] + (tid + 256) * 8); \
    GLDS16(btile + (size_t)(kt) * 4096 + (tid + 384) * 8, (short*)Bb[buf] + (tid + 384) * 8); \
  } while (0)

    auto compute = [&](int buf) {
      bf16x8 af[8], bfv[4];
#pragma unroll
      for (int mf = 0; mf < 8; ++mf)
        af[mf] = *reinterpret_cast<const bf16x8*>(&Ab[buf][mf * 16 + lrow][lkg << 3]);
#pragma unroll
      for (int nf = 0; nf < 4; ++nf) {
        const int nloc = wnh + nf * 16 + lrow;
        const int kg = (lkg ^ ((nloc >> 1) & 3)) << 3;
        bfv[nf] = *reinterpret_cast<const bf16x8*>(&Bb[buf][nloc][kg]);
      }
#pragma unroll
      for (int mf = 0; mf < 8; ++mf)
#pragma unroll
        for (int nf = 0; nf < 4; ++nf)
          acc[mf][nf] = __builtin_amdgcn_mfma_f32_16x16x32_bf16(af[mf], bfv[nf], acc[mf][nf], 0, 0, 0);
    };

    STAGE_D(0, 0); STAGE_D(1, 1); STAGE_D(2, 2);
    VMCNT(16);
    PLAIN_BAR();

    int cb = 0;
    for (int i = 0; i < KT; ++i) {
      compute(cb);
      LGKM_BAR();
      if (i + 3 < KT)      { STAGE_D(i + 3, cb); VMCNT(16); }
      else if (i + 2 < KT) { VMCNT(8); }
      else if (i + 1 < KT) { VMCNT(0); }
      PLAIN_BAR();
      cb = (cb == 2) ? 0 : cb + 1;
    }

#pragma unroll
    for (int mf = 0; mf < 8; ++mf) {
#pragma unroll
      for (int r = 0; r < 4; ++r) {
        const int row = mf * 16 + ((lane >> 4) << 2) + r;
        const int colb = ntile + wnh + lrow;
        if (expert) {
          if (mtile + row < cnt) {
            const int gr = rowbase + mtile + row;
            const float sc = wrow[gr];
            float* o = Out + (size_t)gr * HDIM + colb;
#pragma unroll
            for (int nf = 0; nf < 4; ++nf) o[nf * 16] = sc * acc[mf][nf][r];
          }
        } else {
          float* o = Out + (size_t)(mtile + row) * HDIM + colb;
#pragma unroll
          for (int nf = 0; nf < 4; ++nf) o[nf * 16] = acc[mf][nf][r];
        }
      }
    }
#undef STAGE_D
  }
}

// ---------------- final combine: out[t] += pairs[g0] + pairs[g1]
__global__ void combine_kernel(float* __restrict__ out, const float* __restrict__ pairs,
                               const int* __restrict__ pairpos) {
  const int t = blockIdx.x;
  const int g0 = pairpos[t * 2], g1 = pairpos[t * 2 + 1];
  const f32x4* p0 = (const f32x4*)(pairs + (size_t)g0 * HDIM);
  const f32x4* p1 = (const f32x4*)(pairs + (size_t)g1 * HDIM);
  f32x4* o = (f32x4*)(out + (size_t)t * HDIM);
  for (int c = threadIdx.x; c < HDIM / 4; c += 256)
    o[c] = o[c] + p0[c] + p1[c];
}

extern "C" void kernel_launch(void* const* d_in, const int* in_sizes, int n_in,
                              void* d_out, int out_size, void* d_ws, size_t ws_size,
                              hipStream_t stream) {
  const float* x  = (const float*)d_in[0];
  const float* rw = (const float*)d_in[1];
  const float* w1 = (const float*)d_in[2];
  const float* w3 = (const float*)d_in[3];
  const float* w2 = (const float*)d_in[4];
  const float* sg = (const float*)d_in[5];
  const float* su = (const float*)d_in[6];
  const float* sd = (const float*)d_in[7];
  float* out = (float*)d_out;
  (void)in_sizes; (void)n_in; (void)out_size;

  char* ws = (char*)d_ws;
  size_t off = 0;
  auto alloc = [&](size_t bytes) -> void* {
    void* p = ws + off;
    off = (off + bytes + 255) & ~(size_t)255;
    return p;
  };
  int*   counts  = (int*)alloc(NEXP * 4);          // @0
  int*   slotc   = (int*)alloc(NEXP * 4);          // @256
  int*   offsets = (int*)alloc(NEXP * 4);
  int*   meta    = (int*)alloc(32 * 4);
  int*   tidx    = (int*)alloc(NPAIR * 4);
  float* tw      = (float*)alloc(NPAIR * 4);
  float* wrowv   = (float*)alloc(NPAIR * 4);
  int*   pairpos = (int*)alloc(NPAIR * 4);
  short* xb      = (short*)alloc((size_t)TOKENS * HDIM * 2);
  short* xg      = (short*)alloc((size_t)NPAIR * HDIM * 2);
  short* hbE     = (short*)alloc((size_t)NPAIR * IDIM * 2);
  short* hbS     = (short*)alloc((size_t)TOKENS * ISDIM * 2);
  float* pairs   = (float*)alloc((size_t)NPAIR * HDIM * 4);
  // converted-weight regions
  short* cwA  = (short*)alloc((size_t)NEXP * HDIM * IDIM * 2);   // w1' (reused w2' if no fold)
  short* cwB  = (short*)alloc((size_t)NEXP * HDIM * IDIM * 2);   // w3'
  short* cwS1 = (short*)alloc((size_t)HDIM * ISDIM * 2);         // sg' (reused sd' if no fold)
  short* cwS2 = (short*)alloc((size_t)HDIM * ISDIM * 2);         // su'
  // fold regions (only used if workspace permits)
  short* cw2d = (short*)alloc((size_t)NEXP * IDIM * HDIM * 2);   // +136.3 MB
  short* csdd = (short*)alloc((size_t)ISDIM * HDIM * 2);         // +17.0 MB
  const bool fold = (off <= ws_size);

  hipMemsetAsync(d_ws, 0, 512, stream);  // zero counts + slotc

  router_kernel<<<dim3(TOKENS), dim3(64), 0, stream>>>(x, rw, counts, tidx, tw);
  scan_kernel<<<dim3(1), dim3(64), 0, stream>>>(counts, offsets, meta);
  gather_kernel<<<dim3(TOKENS), dim3(256), 0, stream>>>(x, tidx, tw, offsets, slotc,
                                                        pairpos, wrowv, xb, xg);

  // convert up-phase weights: [K][N] fp32 -> swizzled tile-linear bf16
  wconv_kernel<<<dim3(NEXP * 26 * 80), dim3(256), 0, stream>>>(w1, cwA, HDIM, IDIM, 26, 80, 64);
  wconv_kernel<<<dim3(NEXP * 26 * 80), dim3(256), 0, stream>>>(w3, cwB, HDIM, IDIM, 26, 80, 64);
  wconv_kernel<<<dim3(52 * 80), dim3(256), 0, stream>>>(sg, cwS1, HDIM, ISDIM, 52, 80, 64);
  wconv_kernel<<<dim3(52 * 80), dim3(256), 0, stream>>>(su, cwS2, HDIM, ISDIM, 52, 80, 64);

  // merged up (persistent): GEMM tickets + (if fold) w2/sd conversion tickets
  moe_up_k<<<dim3(NPERS), dim3(128), 0, stream>>>(
      xg, xb, cwA, cwB, cwS1, cwS2, hbE, hbS, counts, offsets, meta,
      w2, sd, fold ? cw2d : cwA, fold ? csdd : cwS1, fold ? 1 : 0);

  if (!fold) {
    // fallback: convert down-phase weights into the freed up-phase regions
    wconv_kernel<<<dim3(NEXP * 20 * 52), dim3(256), 0, stream>>>(w2, cwA, IDIM, HDIM, 20, 52, 128);
    wconv_kernel<<<dim3(20 * 104), dim3(256), 0, stream>>>(sd, cwS1, ISDIM, HDIM, 20, 104, 128);
  }

  // merged down: persistent 768 blocks
  moe_dn_k<<<dim3(NPERS), dim3(128), 0, stream>>>(
      hbE, hbS, fold ? cw2d : cwA, fold ? csdd : cwS1,
      pairs, out, counts, offsets, wrowv, meta);

  combine_kernel<<<dim3(TOKENS), dim3(256), 0, stream>>>(out, pairs, pairpos);
}

// Round 13
// 793.281 us; speedup vs baseline: 1.1128x; 1.1128x over previous
//
#include <hip/hip_runtime.h>
#include <hip/hip_bf16.h>

#define TOKENS 2048
#define HDIM   2560
#define NEXP   16
#define IDIM   1664
#define ISDIM  3328
#define NPAIR  (TOKENS*2)
#define NPERS  768   // persistent blocks (3/CU x 256)

typedef float  f32x4   __attribute__((ext_vector_type(4)));
typedef __bf16 bf16x8  __attribute__((ext_vector_type(8)));
typedef short  short8v __attribute__((ext_vector_type(8)));

#define GLDS16(g, l) __builtin_amdgcn_global_load_lds( \
    (const __attribute__((address_space(1))) unsigned int*)(g), \
    (__attribute__((address_space(3))) unsigned int*)(l), 16, 0, 0)

#define VMCNT(n) asm volatile("s_waitcnt vmcnt(" #n ")" ::: "memory")
#define LGKM_BAR() do { \
    asm volatile("s_waitcnt lgkmcnt(0)" ::: "memory"); \
    __builtin_amdgcn_sched_barrier(0); \
    __builtin_amdgcn_s_barrier(); \
    __builtin_amdgcn_sched_barrier(0); \
  } while (0)

__device__ __forceinline__ short f2bf(float f) {
  unsigned u = __builtin_bit_cast(unsigned, f);
  u += 0x7FFFu + ((u >> 16) & 1u);          // RNE to bf16
  return (short)(u >> 16);
}

// ---------------- router: fp32 logits, softmax-top2-renorm == sigmoid(l0-l1)
__global__ void router_kernel(const float* __restrict__ x, const float* __restrict__ rw,
                              int* __restrict__ counts, int* __restrict__ tidx,
                              float* __restrict__ tw) {
  const int t = blockIdx.x;
  const int lane = threadIdx.x;
  float acc[NEXP];
#pragma unroll
  for (int e = 0; e < NEXP; ++e) acc[e] = 0.f;
  const float* xr = x + (size_t)t * HDIM;
  for (int k = lane; k < HDIM; k += 64) {
    float xv = xr[k];
#pragma unroll
    for (int e = 0; e < NEXP; ++e) acc[e] += xv * rw[e * HDIM + k];
  }
#pragma unroll
  for (int e = 0; e < NEXP; ++e) {
#pragma unroll
    for (int o = 32; o > 0; o >>= 1) acc[e] += __shfl_down(acc[e], o);
  }
  if (lane == 0) {
    int i0 = 0; float v0 = acc[0];
#pragma unroll
    for (int e = 1; e < NEXP; ++e) if (acc[e] > v0) { v0 = acc[e]; i0 = e; }
    int i1 = -1; float v1 = -3.4e38f;
#pragma unroll
    for (int e = 0; e < NEXP; ++e) if (e != i0 && acc[e] > v1) { v1 = acc[e]; i1 = e; }
    float w0 = 1.f / (1.f + expf(v1 - v0));
    tidx[t * 2] = i0; tidx[t * 2 + 1] = i1;
    tw[t * 2] = w0;   tw[t * 2 + 1] = 1.f - w0;
    atomicAdd(&counts[i0], 1);
    atomicAdd(&counts[i1], 1);
  }
}

// scan + tile-queue metadata: meta[0..15]=panel prefix, meta[16]=total panels
__global__ void scan_kernel(const int* __restrict__ counts, int* __restrict__ offsets,
                            int* __restrict__ meta) {
  if (threadIdx.x == 0) {
    int a = 0, p = 0;
    for (int e = 0; e < NEXP; ++e) {
      offsets[e] = a;
      meta[e] = p;
      a += counts[e];
      p += (counts[e] + 127) >> 7;     // ceil(cnt/128) panels
    }
    meta[16] = p;
  }
}

// ---------------- bucket pairs + gather bf16 activations
__global__ void gather_kernel(const float* __restrict__ x, const int* __restrict__ tidx,
                              const float* __restrict__ tw, const int* __restrict__ offsets,
                              int* __restrict__ slotc, int* __restrict__ pairpos,
                              float* __restrict__ wrow, short* __restrict__ xb,
                              short* __restrict__ xg) {
  const int t = blockIdx.x, tid = threadIdx.x;
  __shared__ int grs[2];
  if (tid < 2) {
    int e = tidx[t * 2 + tid];
    int slot = atomicAdd(&slotc[e], 1);
    int g = offsets[e] + slot;
    grs[tid] = g;
    pairpos[t * 2 + tid] = g;
    wrow[g] = tw[t * 2 + tid];
  }
  __syncthreads();
  const int g0 = grs[0], g1 = grs[1];
  const float* xr = x + (size_t)t * HDIM;
#pragma unroll
  for (int i = 0; i < HDIM / 256; ++i) {
    int k = tid + i * 256;
    short v = f2bf(xr[k]);
    xb[(size_t)t * HDIM + k] = v;
    xg[(size_t)g0 * HDIM + k] = v;
    xg[(size_t)g1 * HDIM + k] = v;
  }
}

// ---------------- weight convert: fp32 [K][N] (N-contig) -> bf16 tile-linear,
// pre-swizzled so a linear global_load_lds produces LDS [BN][32] with 16B-unit
// index  n*4 + (koct ^ ((n>>1)&3))  -- matching the GEMM read swizzle exactly.
__global__ void wconv_kernel(const float* __restrict__ src, short* __restrict__ dst,
                             const int K, const int N, const int nT, const int kT,
                             const int BN) {
  const int tid = threadIdx.x;
  int b = blockIdx.x;
  const int kt = b % kT;
  b /= kT;
  const int nt = b % nT;
  const int slab = b / nT;
  const float* s0 = src + (size_t)slab * K * N + (size_t)(kt * 32) * N + nt * BN;
  short8v* d = (short8v*)(dst + ((size_t)((slab * nT + nt) * kT + kt)) * BN * 32);
  const int upt = BN >> 6;                 // units per thread (1 or 2)
  for (int q = 0; q < upt; ++q) {
    const int uidx = tid + q * 256;
    const int n = uidx >> 2;
    const int u = uidx & 3;
    const int koct = u ^ ((n >> 1) & 3);
    const float* s = s0 + (size_t)(koct * 8) * N + n;
    short8v v;
#pragma unroll
    for (int j = 0; j < 8; ++j) v[j] = f2bf(s[(size_t)j * N]);
    d[uidx] = v;
  }
}

// ================= merged UP (persistent, 256 thr = 4 waves):
// H = bf16( silu(A*B1) * (A*B3) ).  Block tile 128m x 64n x {G,U}.
// Wave w: m-half (w&1), mat (w>>1); wave tile 64x64.
// SINGLE barrier per K-step: buffer freed at step i-1 receives tile i+2
// after the step-i barrier; VMCNT(4) before the barrier proves stage(i) done.
__launch_bounds__(256, 3)
__global__ void moe_up_k(const short* __restrict__ xg, const short* __restrict__ xb,
                         const short* __restrict__ cw1, const short* __restrict__ cw3,
                         const short* __restrict__ csg, const short* __restrict__ csu,
                         short* __restrict__ hbE, short* __restrict__ hbS,
                         const int* __restrict__ counts, const int* __restrict__ offsets,
                         const int* __restrict__ meta) {
  const int tid = threadIdx.x;
  __shared__ int spre[17];
  __shared__ __align__(16) char pool[49152];
  short (*Ab)[128][32] = (short(*)[128][32])pool;             // [3][128][32]  24KB
  short (*Bb)[128][32] = (short(*)[128][32])(pool + 24576);   // [3][G64|U64][32] 24KB
  float* scratch = (float*)pool;                              // 32KB, epilogue only

  if (tid < 17) spre[tid] = meta[tid];
  __syncthreads();
  const int gemmE = spre[16] * 26;
  const int total = gemmE + 832;

  const int lane = tid & 63;
  const int w = tid >> 6;
  const int wmv = (w & 1) * 64;     // m-half
  const int mat = w >> 1;           // 0=G, 1=U
  const int lrow = lane & 15;
  const int lkg = lane >> 4;
  const int a_ko = (tid & 3) << 3;

  for (int ticket = blockIdx.x; ticket < total; ticket += NPERS) {
    const short* A; const short* b1tile; const short* b3tile; short* H;
    int N, mtile, ntile, rowbase = 0, cnt = 0x7fffffff;
    bool expert;
    if (ticket < gemmE) {
      const int p = ticket / 26;
      const int n = ticket % 26;
      int e = 0;
#pragma unroll
      for (int i = 1; i < 16; ++i) if (p >= spre[i]) e = i;
      const int m = p - spre[e];
      cnt = counts[e];
      rowbase = offsets[e];
      mtile = m * 128;
      A = xg;
      b1tile = cw1 + ((size_t)((e * 26 + n) * 80)) * 2048;
      b3tile = cw3 + ((size_t)((e * 26 + n) * 80)) * 2048;
      H = hbE; N = IDIM; ntile = n * 64; expert = true;
    } else {
      const int s = ticket - gemmE;   // 0..831
      const int n = s % 52;
      const int m = s / 52;           // 0..15
      mtile = m * 128;
      A = xb;
      b1tile = csg + ((size_t)(n * 80)) * 2048;
      b3tile = csu + ((size_t)(n * 80)) * 2048;
      H = hbS; N = ISDIM; ntile = n * 64; expert = false;
    }
    const int K = HDIM;
    const int KT = HDIM / 32;         // 80

    f32x4 acc[4][4];
#pragma unroll
    for (int i = 0; i < 4; ++i)
#pragma unroll
      for (int j = 0; j < 4; ++j) { f32x4 z = {0.f,0.f,0.f,0.f}; acc[i][j] = z; }

    int gr0, gr1;
    {
      int r0 = tid >> 2, r1 = (tid >> 2) + 64;
      gr0 = expert ? (rowbase + mtile + r0) : (mtile + r0);
      gr1 = expert ? (rowbase + mtile + r1) : (mtile + r1);
      if (gr0 > NPAIR - 1) gr0 = NPAIR - 1;
      if (gr1 > NPAIR - 1) gr1 = NPAIR - 1;
    }
    const short* a_src0 = A + (size_t)gr0 * K + a_ko;
    const short* a_src1 = A + (size_t)gr1 * K + a_ko;

#define STAGE_U(kt, buf) do { \
    GLDS16(a_src0 + ((kt) << 5), (short*)Ab[buf] + tid * 8); \
    GLDS16(a_src1 + ((kt) << 5), (short*)Ab[buf] + (tid + 256) * 8); \
    GLDS16(b1tile + (size_t)(kt) * 2048 + tid * 8, (short*)Bb[buf] + tid * 8); \
    GLDS16(b3tile + (size_t)(kt) * 2048 + tid * 8, (short*)Bb[buf] + 2048 + tid * 8); \
  } while (0)

    auto compute = [&](int buf) {
      bf16x8 af[4], bfv[4];
#pragma unroll
      for (int mf = 0; mf < 4; ++mf)
        af[mf] = *reinterpret_cast<const bf16x8*>(&Ab[buf][wmv + mf * 16 + lrow][lkg << 3]);
#pragma unroll
      for (int nf = 0; nf < 4; ++nf) {
        const int nloc = nf * 16 + lrow;
        const int kg = (lkg ^ ((nloc >> 1) & 3)) << 3;
        bfv[nf] = *reinterpret_cast<const bf16x8*>(&Bb[buf][mat * 64 + nloc][kg]);
      }
#pragma unroll
      for (int mf = 0; mf < 4; ++mf)
#pragma unroll
        for (int nf = 0; nf < 4; ++nf)
          acc[mf][nf] = __builtin_amdgcn_mfma_f32_16x16x32_bf16(af[mf], bfv[nf], acc[mf][nf], 0, 0, 0);
    };

    // single-barrier pipelined K-loop (depth-3, stage 2 ahead)
    STAGE_U(0, 0); STAGE_U(1, 1);
    for (int i = 0; i < KT; ++i) {
      if (i + 1 < KT) { VMCNT(4); } else { VMCNT(0); }
      LGKM_BAR();
      if (i + 2 < KT) {
        const int fb = (i + 2) % 3;
        STAGE_U(i + 2, fb);
      }
      compute(i % 3);
    }
    LGKM_BAR();   // all compute reads done before scratch writes

    // epilogue: U-waves export acc to scratch; G-waves fuse silu(g)*u -> H.
    if (mat) {
      float* sc = scratch + (size_t)(w & 1) * 4096;
#pragma unroll
      for (int mf = 0; mf < 4; ++mf)
#pragma unroll
        for (int r = 0; r < 4; ++r) {
          const int row = mf * 16 + ((lane >> 4) << 2) + r;
#pragma unroll
          for (int nf = 0; nf < 4; ++nf)
            sc[row * 64 + nf * 16 + lrow] = acc[mf][nf][r];
        }
    }
    LGKM_BAR();
    if (!mat) {
      const float* sc = scratch + (size_t)(w & 1) * 4096;
#pragma unroll
      for (int mf = 0; mf < 4; ++mf) {
#pragma unroll
        for (int r = 0; r < 4; ++r) {
          const int row = mf * 16 + ((lane >> 4) << 2) + r;
          const int rt = wmv + row;
          if (expert && mtile + rt >= cnt) continue;
          const size_t grow = (size_t)((expert ? rowbase : 0) + mtile + rt);
          const int colb = ntile + lrow;
#pragma unroll
          for (int nf = 0; nf < 4; ++nf) {
            float g = acc[mf][nf][r];
            float u = sc[row * 64 + nf * 16 + lrow];
            H[grow * N + colb + nf * 16] = f2bf(g / (1.f + expf(-g)) * u);
          }
        }
      }
    }
    LGKM_BAR();   // scratch reads complete before next ticket's staging
#undef STAGE_U
  }
}

// ================= merged DOWN (persistent, 256 thr = 4 waves): Out = A*B.
// Block tile 128m x 128n; wave tile 64x64.  Single-barrier K-loop.
// Shared tiles (KT=104) ticketed FIRST so long tiles never start in the tail.
__launch_bounds__(256, 3)
__global__ void moe_dn_k(const short* __restrict__ hbE, const short* __restrict__ hbS,
                         const short* __restrict__ cw2, const short* __restrict__ csd,
                         float* __restrict__ pairs, float* __restrict__ outb,
                         const int* __restrict__ counts, const int* __restrict__ offsets,
                         const float* __restrict__ wrow, const int* __restrict__ meta) {
  const int tid = threadIdx.x;
  __shared__ int spre[17];
  __shared__ short Ab[3][128][32];   // 24 KB, linear
  __shared__ short Bb[3][128][32];   // 24 KB, swizzled [n][k] tile-linear

  if (tid < 17) spre[tid] = meta[tid];
  __syncthreads();
  const int total = spre[16] * 20 + 320;

  const int lane = tid & 63;
  const int w = tid >> 6;
  const int wm = (w >> 1) * 64;
  const int wn = (w & 1) * 64;
  const int lrow = lane & 15;
  const int lkg = lane >> 4;
  const int a_ko = (tid & 3) << 3;

  for (int ticket = blockIdx.x; ticket < total; ticket += NPERS) {
    const short* A; const short* btile; float* Out;
    int K, KT, mtile, ntile, rowbase = 0, cnt = 0x7fffffff;
    bool expert;
    if (ticket < 320) {               // shared first (long tiles)
      const int n = ticket % 20;
      const int m = ticket / 20;      // 0..15
      mtile = m * 128;
      A = hbS;
      btile = csd + ((size_t)(n * 104)) * 4096;
      Out = outb; K = ISDIM; KT = ISDIM / 32; ntile = n * 128; expert = false; // KT=104
    } else {
      const int te = ticket - 320;
      const int p = te / 20;
      const int n = te % 20;
      int e = 0;
#pragma unroll
      for (int i = 1; i < 16; ++i) if (p >= spre[i]) e = i;
      const int m = p - spre[e];
      cnt = counts[e];
      rowbase = offsets[e];
      mtile = m * 128;
      A = hbE;
      btile = cw2 + ((size_t)((e * 20 + n) * 52)) * 4096;
      Out = pairs; K = IDIM; KT = IDIM / 32; ntile = n * 128; expert = true;   // KT=52
    }

    f32x4 acc[4][4];
#pragma unroll
    for (int i = 0; i < 4; ++i)
#pragma unroll
      for (int j = 0; j < 4; ++j) { f32x4 z = {0.f,0.f,0.f,0.f}; acc[i][j] = z; }

    int gr0, gr1;
    {
      int r0 = tid >> 2, r1 = (tid >> 2) + 64;
      gr0 = expert ? (rowbase + mtile + r0) : (mtile + r0);
      gr1 = expert ? (rowbase + mtile + r1) : (mtile + r1);
      if (gr0 > NPAIR - 1) gr0 = NPAIR - 1;
      if (gr1 > NPAIR - 1) gr1 = NPAIR - 1;
    }
    const short* a_src0 = A + (size_t)gr0 * K + a_ko;
    const short* a_src1 = A + (size_t)gr1 * K + a_ko;

#define STAGE_D(kt, buf) do { \
    GLDS16(a_src0 + ((kt) << 5), (short*)Ab[buf] + tid * 8); \
    GLDS16(a_src1 + ((kt) << 5), (short*)Ab[buf] + (tid + 256) * 8); \
    GLDS16(btile + (size_t)(kt) * 4096 + tid * 8, (short*)Bb[buf] + tid * 8); \
    GLDS16(btile + (size_t)(kt) * 4096 + (tid + 256) * 8, (short*)Bb[buf] + (tid + 256) * 8); \
  } while (0)

    auto compute = [&](int buf) {
      bf16x8 af[4], bfv[4];
#pragma unroll
      for (int mf = 0; mf < 4; ++mf)
        af[mf] = *reinterpret_cast<const bf16x8*>(&Ab[buf][wm + mf * 16 + lrow][lkg << 3]);
#pragma unroll
      for (int nf = 0; nf < 4; ++nf) {
        const int n = wn + nf * 16 + lrow;
        const int kg = (lkg ^ ((n >> 1) & 3)) << 3;
        bfv[nf] = *reinterpret_cast<const bf16x8*>(&Bb[buf][n][kg]);
      }
#pragma unroll
      for (int mf = 0; mf < 4; ++mf)
#pragma unroll
        for (int nf = 0; nf < 4; ++nf)
          acc[mf][nf] = __builtin_amdgcn_mfma_f32_16x16x32_bf16(af[mf], bfv[nf], acc[mf][nf], 0, 0, 0);
    };

    // single-barrier pipelined K-loop (depth-3, stage 2 ahead)
    STAGE_D(0, 0); STAGE_D(1, 1);
    for (int i = 0; i < KT; ++i) {
      if (i + 1 < KT) { VMCNT(4); } else { VMCNT(0); }
      LGKM_BAR();
      if (i + 2 < KT) {
        const int fb = (i + 2) % 3;
        STAGE_D(i + 2, fb);
      }
      compute(i % 3);
    }

#pragma unroll
    for (int mf = 0; mf < 4; ++mf) {
#pragma unroll
      for (int r = 0; r < 4; ++r) {
        const int rt = wm + mf * 16 + ((lane >> 4) << 2) + r;
        const int colb = ntile + wn + lrow;
        if (expert) {
          if (mtile + rt < cnt) {
            const int gr = rowbase + mtile + rt;
            const float sc = wrow[gr];
            float* o = Out + (size_t)gr * HDIM + colb;
#pragma unroll
            for (int nf = 0; nf < 4; ++nf) o[nf * 16] = sc * acc[mf][nf][r];
          }
        } else {
          float* o = Out + (size_t)(mtile + rt) * HDIM + colb;
#pragma unroll
          for (int nf = 0; nf < 4; ++nf) o[nf * 16] = acc[mf][nf][r];
        }
      }
    }
    LGKM_BAR();   // final compute reads complete before next ticket's staging
#undef STAGE_D
  }
}

// ---------------- final combine: out[t] += pairs[g0] + pairs[g1]
__global__ void combine_kernel(float* __restrict__ out, const float* __restrict__ pairs,
                               const int* __restrict__ pairpos) {
  const int t = blockIdx.x;
  const int g0 = pairpos[t * 2], g1 = pairpos[t * 2 + 1];
  const f32x4* p0 = (const f32x4*)(pairs + (size_t)g0 * HDIM);
  const f32x4* p1 = (const f32x4*)(pairs + (size_t)g1 * HDIM);
  f32x4* o = (f32x4*)(out + (size_t)t * HDIM);
  for (int c = threadIdx.x; c < HDIM / 4; c += 256)
    o[c] = o[c] + p0[c] + p1[c];
}

extern "C" void kernel_launch(void* const* d_in, const int* in_sizes, int n_in,
                              void* d_out, int out_size, void* d_ws, size_t ws_size,
                              hipStream_t stream) {
  const float* x  = (const float*)d_in[0];
  const float* rw = (const float*)d_in[1];
  const float* w1 = (const float*)d_in[2];
  const float* w3 = (const float*)d_in[3];
  const float* w2 = (const float*)d_in[4];
  const float* sg = (const float*)d_in[5];
  const float* su = (const float*)d_in[6];
  const float* sd = (const float*)d_in[7];
  float* out = (float*)d_out;
  (void)in_sizes; (void)n_in; (void)out_size; (void)ws_size;

  char* ws = (char*)d_ws;
  size_t off = 0;
  auto alloc = [&](size_t bytes) -> void* {
    void* p = ws + off;
    off = (off + bytes + 255) & ~(size_t)255;
    return p;
  };
  int*   counts  = (int*)alloc(NEXP * 4);          // @0
  int*   slotc   = (int*)alloc(NEXP * 4);          // @256
  int*   offsets = (int*)alloc(NEXP * 4);
  int*   meta    = (int*)alloc(32 * 4);
  int*   tidx    = (int*)alloc(NPAIR * 4);
  float* tw      = (float*)alloc(NPAIR * 4);
  float* wrowv   = (float*)alloc(NPAIR * 4);
  int*   pairpos = (int*)alloc(NPAIR * 4);
  short* xb      = (short*)alloc((size_t)TOKENS * HDIM * 2);
  short* xg      = (short*)alloc((size_t)NPAIR * HDIM * 2);
  short* hbE     = (short*)alloc((size_t)NPAIR * IDIM * 2);
  short* hbS     = (short*)alloc((size_t)TOKENS * ISDIM * 2);
  float* pairs   = (float*)alloc((size_t)NPAIR * HDIM * 4);
  // converted-weight regions (phase-reused): cwA holds w1' then w2'; cwS1 sg' then sd'
  short* cwA  = (short*)alloc((size_t)NEXP * HDIM * IDIM * 2);   // 136.3 MB
  short* cwB  = (short*)alloc((size_t)NEXP * HDIM * IDIM * 2);   // 136.3 MB
  short* cwS1 = (short*)alloc((size_t)HDIM * ISDIM * 2);         // 17.0 MB
  short* cwS2 = (short*)alloc((size_t)HDIM * ISDIM * 2);         // 17.0 MB

  hipMemsetAsync(d_ws, 0, 512, stream);  // zero counts + slotc

  router_kernel<<<dim3(TOKENS), dim3(64), 0, stream>>>(x, rw, counts, tidx, tw);
  scan_kernel<<<dim3(1), dim3(64), 0, stream>>>(counts, offsets, meta);
  gather_kernel<<<dim3(TOKENS), dim3(256), 0, stream>>>(x, tidx, tw, offsets, slotc,
                                                        pairpos, wrowv, xb, xg);

  // convert up-phase weights: [K][N] fp32 -> swizzled tile-linear bf16
  wconv_kernel<<<dim3(NEXP * 26 * 80), dim3(256), 0, stream>>>(w1, cwA, HDIM, IDIM, 26, 80, 64);
  wconv_kernel<<<dim3(NEXP * 26 * 80), dim3(256), 0, stream>>>(w3, cwB, HDIM, IDIM, 26, 80, 64);
  wconv_kernel<<<dim3(52 * 80), dim3(256), 0, stream>>>(sg, cwS1, HDIM, ISDIM, 52, 80, 64);
  wconv_kernel<<<dim3(52 * 80), dim3(256), 0, stream>>>(su, cwS2, HDIM, ISDIM, 52, 80, 64);

  // merged up: persistent 768 blocks over compact ticket space
  moe_up_k<<<dim3(NPERS), dim3(256), 0, stream>>>(
      xg, xb, cwA, cwB, cwS1, cwS2, hbE, hbS, counts, offsets, meta);

  // convert down-phase weights into the freed regions
  wconv_kernel<<<dim3(NEXP * 20 * 52), dim3(256), 0, stream>>>(w2, cwA, IDIM, HDIM, 20, 52, 128);
  wconv_kernel<<<dim3(20 * 104), dim3(256), 0, stream>>>(sd, cwS1, ISDIM, HDIM, 20, 104, 128);

  // merged down: persistent 768 blocks
  moe_dn_k<<<dim3(NPERS), dim3(256), 0, stream>>>(
      hbE, hbS, cwA, cwS1, pairs, out, counts, offsets, wrowv, meta);

  combine_kernel<<<dim3(TOKENS), dim3(256), 0, stream>>>(out, pairs, pairpos);
}